// Round 1
// baseline (25.266 us; speedup 1.0000x reference)
//
#include <hip/hip_runtime.h>

#define BATCH 512
#define DIM 128
#define MARGIN 1.0f

__global__ __launch_bounds__(256) void triplet_main_kernel(
    const float* __restrict__ emb, const int* __restrict__ labels,
    double* __restrict__ loss_part, int* __restrict__ cnt_part)
{
    const int a = blockIdx.x;
    const int tid = threadIdx.x;

    __shared__ float ea[DIM];
    __shared__ float drow[BATCH];
    __shared__ float posd[BATCH];
    __shared__ int lbls[BATCH];
    __shared__ int npos;
    __shared__ float rsum[256];
    __shared__ int rcnt[256];

    // Load anchor embedding and all labels into LDS.
    if (tid < DIM) ea[tid] = emb[a * DIM + tid];
    if (tid == 0) npos = 0;
    for (int j = tid; j < BATCH; j += 256) lbls[j] = labels[j];
    __syncthreads();

    const int la = lbls[a];

    // Distance row: drow[j] = ||e_a - e_j||^2, float4-vectorized.
    const float4* eav = reinterpret_cast<const float4*>(ea);
    for (int j = tid; j < BATCH; j += 256) {
        const float4* ej = reinterpret_cast<const float4*>(emb + (size_t)j * DIM);
        float acc = 0.f;
        #pragma unroll
        for (int d4 = 0; d4 < DIM / 4; ++d4) {
            float4 vj = ej[d4];
            float4 va = eav[d4];
            float dx = va.x - vj.x;
            float dy = va.y - vj.y;
            float dz = va.z - vj.z;
            float dw = va.w - vj.w;
            acc += dx * dx + dy * dy + dz * dz + dw * dw;
        }
        drow[j] = acc;
    }
    __syncthreads();

    // Gather positive distances (same label, j != a).
    for (int j = tid; j < BATCH; j += 256) {
        if (j != a && lbls[j] == la) {
            int idx = atomicAdd(&npos, 1);
            posd[idx] = drow[j];
        }
    }
    __syncthreads();

    const int np = npos;

    // Accumulate relu(d_ap - d_an + margin) over (pos, neg) pairs.
    float lsum = 0.f;
    int lcnt = 0;
    for (int n = tid; n < BATCH; n += 256) {
        if (lbls[n] != la) {
            const float dan_m = MARGIN - drow[n];
            for (int p = 0; p < np; ++p) {
                float t = posd[p] + dan_m;
                lsum += (t > 0.f) ? t : 0.f;
            }
            lcnt += np;
        }
    }

    // Block reduction.
    rsum[tid] = lsum;
    rcnt[tid] = lcnt;
    __syncthreads();
    for (int s = 128; s > 0; s >>= 1) {
        if (tid < s) {
            rsum[tid] += rsum[tid + s];
            rcnt[tid] += rcnt[tid + s];
        }
        __syncthreads();
    }
    if (tid == 0) {
        loss_part[a] = (double)rsum[0];
        cnt_part[a] = rcnt[0];
    }
}

__global__ __launch_bounds__(512) void triplet_finalize_kernel(
    const double* __restrict__ loss_part, const int* __restrict__ cnt_part,
    float* __restrict__ out)
{
    __shared__ double s[BATCH];
    __shared__ long long c[BATCH];
    const int t = threadIdx.x;
    s[t] = loss_part[t];
    c[t] = (long long)cnt_part[t];
    __syncthreads();
    for (int st = 256; st > 0; st >>= 1) {
        if (t < st) {
            s[t] += s[t + st];
            c[t] += c[t + st];
        }
        __syncthreads();
    }
    if (t == 0) out[0] = (float)(s[0] / (double)c[0]);
}

extern "C" void kernel_launch(void* const* d_in, const int* in_sizes, int n_in,
                              void* d_out, int out_size, void* d_ws, size_t ws_size,
                              hipStream_t stream) {
    const float* emb = (const float*)d_in[0];   // [512, 128] f32
    const int* labels = (const int*)d_in[1];    // [512] i32
    float* out = (float*)d_out;                 // scalar f32

    double* loss_part = (double*)d_ws;                         // 512 doubles
    int* cnt_part = (int*)((char*)d_ws + BATCH * sizeof(double)); // 512 ints

    triplet_main_kernel<<<BATCH, 256, 0, stream>>>(emb, labels, loss_part, cnt_part);
    triplet_finalize_kernel<<<1, BATCH, 0, stream>>>(loss_part, cnt_part, out);
}